// Round 1
// baseline (371.762 us; speedup 1.0000x reference)
//
#include <hip/hip_runtime.h>

#define HW   4096
#define CHW  262144
#define NPQ  441
#define KPAD 448

typedef __attribute__((ext_vector_type(8))) short bf16x8;
typedef __attribute__((ext_vector_type(4))) float f32x4;

#define MFMA16(a,b,c) __builtin_amdgcn_mfma_f32_16x16x32_bf16(a,b,c,0,0,0)

__device__ __forceinline__ short f2bf(float f){
  unsigned u = __float_as_uint(f);
  return (short)((u + 0x7FFFu + ((u >> 16) & 1u)) >> 16);
}

// Load an A/B fragment for mfma_f32_16x16x32_bf16 from a row of f1/f2.
// Matrix element [idx16 = tile*16 + (lane&15)][k = (lane>>4)*8 + j], where
// matrix[i][c] = row[c*HW + 2*i + pi]  (parity-split column, channel-major).
__device__ __forceinline__ bf16x8 load_frag(const float* rowp, int pi, int tile,
                                            int kk, int lane){
  const int m = lane & 15, kg = lane >> 4;
  const float* p = rowp + (kk*32 + kg*8)*HW + 2*(tile*16 + m) + pi;
  bf16x8 r;
#pragma unroll
  for (int j = 0; j < 8; ++j) r[j] = f2bf(p[j*HW]);
  return r;
}

// ---------------- Pass 1: correlation Gram + BN statistics ----------------
__global__ __launch_bounds__(256,2) void k_stats(const float* __restrict__ feats,
                                                 float* __restrict__ gsum,
                                                 float* __restrict__ gssq)
{
  __shared__ float Gbuf[4*1056];          // per-wave 32x32 Gram, col-major stride 33
  __shared__ float s_sum[NPQ];
  __shared__ float s_ssq[NPQ];
  const int tid = threadIdx.x, wv = tid >> 6, lane = tid & 63;
  const int n = blockIdx.x >> 6, h = blockIdx.x & 63;
  const int fbase = ((n/7)*8 + (n%7))*CHW;
  const float* f1  = feats + fbase + h*64;
  const float* f2b = feats + fbase + CHW;
  float* Gw = Gbuf + wv*1056;

  for (int i = tid; i < NPQ; i += 256){ s_sum[i] = 0.f; s_ssq[i] = 0.f; }
  __syncthreads();

  bf16x8 afr[2][2];
  int cur_pi = -1;
  for (int it = 0; it < 11; ++it){
    const int u = it*4 + wv;              // consecutive u across waves -> distinct p
    const bool active = (u < 42);
    const int pi = (u >= 21) ? 1 : 0;
    const int p  = u - pi*21;
    const int row = h + 2*p - 20;
    const bool rv = active && ((unsigned)row < 64u);

    if (active && pi != cur_pi){
#pragma unroll
      for (int mt = 0; mt < 2; ++mt)
#pragma unroll
        for (int kk = 0; kk < 2; ++kk)
          afr[mt][kk] = load_frag(f1, pi, mt, kk, lane);
      cur_pi = pi;
    }

    if (rv){
      const float* f2r = f2b + row*64;
      f32x4 a00 = {0.f,0.f,0.f,0.f}, a01 = a00, a10 = a00, a11 = a00;
#pragma unroll
      for (int kk = 0; kk < 2; ++kk){
        bf16x8 b0 = load_frag(f2r, pi, 0, kk, lane);
        bf16x8 b1 = load_frag(f2r, pi, 1, kk, lane);
        a00 = MFMA16(afr[0][kk], b0, a00);
        a01 = MFMA16(afr[0][kk], b1, a01);
        a10 = MFMA16(afr[1][kk], b0, a10);
        a11 = MFMA16(afr[1][kk], b1, a11);
      }
      const int cI = (lane >> 4)*4;       // C-layout: row=(lane>>4)*4+reg
      const int cJ = lane & 15;           //           col=lane&15
#pragma unroll
      for (int r = 0; r < 4; ++r){
        Gw[(cJ     )*33 + cI + r     ] = a00[r];
        Gw[(cJ + 16)*33 + cI + r     ] = a01[r];
        Gw[(cJ     )*33 + cI + r + 16] = a10[r];
        Gw[(cJ + 16)*33 + cI + r + 16] = a11[r];
      }
    }
    __syncthreads();

    if (rv){
      const int q = lane / 3;             // lanes 0..62 -> q 0..20, seg 0..2
      const int seg = lane - q*3;
      float s = 0.f, s2 = 0.f;
      if (lane < 63){
        const int i0 = seg*11;
        const int i1 = (seg == 2) ? 32 : i0 + 11;
        for (int i = i0; i < i1; ++i){
          const int j = i + q - 10;
          if ((unsigned)j < 32u){
            float v = Gw[j*33 + i];
            s += v; s2 += v*v;
          }
        }
      }
      float sA = __shfl(s,  lane+1), sB = __shfl(s,  lane+2);
      float tA = __shfl(s2, lane+1), tB = __shfl(s2, lane+2);
      if (lane < 63 && seg == 0){
        s_sum[p*21 + q] += s + sA + sB;   // distinct p across waves, barrier-safe
        s_ssq[p*21 + q] += s2 + tA + tB;
      }
    }
    __syncthreads();
  }

  for (int i = tid; i < NPQ; i += 256){
    atomicAdd(&gsum[i], s_sum[i]);
    atomicAdd(&gssq[i], s_ssq[i]);
  }
}

// ---------------- Pass 2a: fold BN into conv weights ----------------
__global__ __launch_bounds__(256) void k_finalize(const float* __restrict__ gsum,
    const float* __restrict__ gssq, const float* __restrict__ gamma,
    const float* __restrict__ beta, const float* __restrict__ convw,
    short* __restrict__ wpT, float* __restrict__ bias)
{
  __shared__ float s_scale[NPQ], s_shift[NPQ];
  const int tid = threadIdx.x;
  for (int k = tid; k < NPQ; k += 256){
    float m  = gsum[k] * (1.f/114688.f);
    float v  = gssq[k] * (1.f/114688.f) - m*m;
    float iv = rsqrtf(v + 1e-5f);
    float sc = gamma[k] * iv;
    s_scale[k] = sc;
    s_shift[k] = beta[k] - m*sc;
  }
  __syncthreads();
  for (int idx = tid; idx < 64*KPAD; idx += 256){
    int o = idx / KPAD, k = idx - o*KPAD;
    float w = (k < NPQ) ? convw[o*NPQ + k] * s_scale[k] : 0.f;
    wpT[idx] = f2bf(w);                   // wpT[o][k], K padded to 448 with zeros
  }
  if (tid < 64){
    float b = 0.f;
    for (int k = 0; k < NPQ; ++k) b += s_shift[k] * convw[tid*NPQ + k];
    bias[tid] = b;
  }
}

// ---------------- Pass 2b: recompute Gram, fused conv, write output ----------------
__global__ __launch_bounds__(256,2) void k_main(const float* __restrict__ feats,
    const short* __restrict__ wpT, const float* __restrict__ bias,
    float* __restrict__ out)
{
  __shared__ __align__(16) short cor[64*456];   // [pixel][448+pad] bf16
  __shared__ float Gbuf[4*1056];
  const int tid = threadIdx.x, wv = tid >> 6, lane = tid & 63;
  const int n = blockIdx.x >> 6, h = blockIdx.x & 63;
  const int fbase = ((n/7)*8 + (n%7))*CHW;
  const float* f1  = feats + fbase + h*64;
  const float* f2b = feats + fbase + CHW;
  float* Gw = Gbuf + wv*1056;

  for (int idx = tid; idx < 64*7; idx += 256)   // zero K-pad columns 441..447
    cor[(idx/7)*456 + 441 + (idx%7)] = 0;

  bf16x8 afr[2][2];
  int cur_pi = -1;
  for (int it = 0; it < 11; ++it){
    const int u = it*4 + wv;
    const bool active = (u < 42);
    const int pi = (u >= 21) ? 1 : 0;
    const int p  = u - pi*21;
    const int row = h + 2*p - 20;
    const bool rv = active && ((unsigned)row < 64u);

    if (active && pi != cur_pi){
#pragma unroll
      for (int mt = 0; mt < 2; ++mt)
#pragma unroll
        for (int kk = 0; kk < 2; ++kk)
          afr[mt][kk] = load_frag(f1, pi, mt, kk, lane);
      cur_pi = pi;
    }

    if (rv){
      const float* f2r = f2b + row*64;
      f32x4 a00 = {0.f,0.f,0.f,0.f}, a01 = a00, a10 = a00, a11 = a00;
#pragma unroll
      for (int kk = 0; kk < 2; ++kk){
        bf16x8 b0 = load_frag(f2r, pi, 0, kk, lane);
        bf16x8 b1 = load_frag(f2r, pi, 1, kk, lane);
        a00 = MFMA16(afr[0][kk], b0, a00);
        a01 = MFMA16(afr[0][kk], b1, a01);
        a10 = MFMA16(afr[1][kk], b0, a10);
        a11 = MFMA16(afr[1][kk], b1, a11);
      }
      const int cI = (lane >> 4)*4;
      const int cJ = lane & 15;
#pragma unroll
      for (int r = 0; r < 4; ++r){
        Gw[(cJ     )*33 + cI + r     ] = a00[r];
        Gw[(cJ + 16)*33 + cI + r     ] = a01[r];
        Gw[(cJ     )*33 + cI + r + 16] = a10[r];
        Gw[(cJ + 16)*33 + cI + r + 16] = a11[r];
      }
    }
    __syncthreads();

    if (active){                           // band -> cor tile (zeros when invalid)
      const int i = lane & 31, half = lane >> 5;
      short* crow = &cor[(2*i + pi)*456 + p*21];
      const int tmax = 11 - half;          // half0: q 0..10, half1: q 11..20
      for (int t = 0; t < tmax; ++t){
        const int q = half*11 + t;
        const int j = i + q - 10;
        float v = (rv && (unsigned)j < 32u) ? Gw[j*33 + i] : 0.f;
        crow[q] = f2bf(v);
      }
    }
    __syncthreads();
  }

  // GEMM2: D[o][pix] = sum_k wpT[o][k] * cor[pix][k]   (M=64 o, N=64 pix, K=448)
  const int m = lane & 15, kg = lane >> 4;
  const short* wrow = wpT + (wv*16 + m)*KPAD;    // A[m=o][k]: contiguous 16B
  f32x4 acc[4];
#pragma unroll
  for (int nt = 0; nt < 4; ++nt) acc[nt] = (f32x4){0.f,0.f,0.f,0.f};
  for (int kk = 0; kk < 14; ++kk){
    const int k0 = kk*32 + kg*8;
    bf16x8 aw = *(const bf16x8*)(wrow + k0);
#pragma unroll
    for (int nt = 0; nt < 4; ++nt){
      bf16x8 bc = *(const bf16x8*)&cor[(nt*16 + m)*456 + k0];  // B[k][n=pix]: ds_read_b128
      acc[nt] = MFMA16(aw, bc, acc[nt]);
    }
  }
  const int r0 = (lane >> 4)*4;
  float bo[4];
#pragma unroll
  for (int r = 0; r < 4; ++r) bo[r] = bias[wv*16 + r0 + r];
  float* outb = out + fbase + h*64;
#pragma unroll
  for (int nt = 0; nt < 4; ++nt)
#pragma unroll
    for (int r = 0; r < 4; ++r){
      const int o = wv*16 + r0 + r;
      outb[o*HW + nt*16 + m] = acc[nt][r] + bo[r];   // 4x64B segments per store
    }
}

// ---------------- zero frame T=7 ----------------
__global__ __launch_bounds__(256) void k_zero(float* __restrict__ out){
  const int idx = blockIdx.x*256 + threadIdx.x;    // 1024 blocks -> 262144 float4
  const int b = idx >> 16, r = idx & 65535;
  float4* p = (float4*)(out + (size_t)(b*8 + 7)*CHW);
  p[r] = make_float4(0.f, 0.f, 0.f, 0.f);
}

extern "C" void kernel_launch(void* const* d_in, const int* in_sizes, int n_in,
                              void* d_out, int out_size, void* d_ws, size_t ws_size,
                              hipStream_t stream)
{
  const float* feats = (const float*)d_in[0];
  const float* gamma = (const float*)d_in[1];
  const float* beta  = (const float*)d_in[2];
  const float* convw = (const float*)d_in[3];
  float* out = (float*)d_out;
  float* wsf = (float*)d_ws;
  float* gsum = wsf;                 // 441 floats
  float* gssq = wsf + 441;           // 441 floats
  float* bias = wsf + 896;           // 64 floats
  short* wpT  = (short*)(wsf + 1024);// [64][448] bf16, 16B-aligned

  hipMemsetAsync(gsum, 0, 882*sizeof(float), stream);
  k_zero<<<1024, 256, 0, stream>>>(out);
  k_stats<<<1792, 256, 0, stream>>>(feats, gsum, gssq);
  k_finalize<<<1, 256, 0, stream>>>(gsum, gssq, gamma, beta, convw, wpT, bias);
  k_main<<<1792, 256, 0, stream>>>(feats, wpT, bias, out);
}

// Round 4
// 285.354 us; speedup vs baseline: 1.3028x; 1.3028x over previous
//
#include <hip/hip_runtime.h>

#define HW   4096
#define CHW  262144
#define NPQ  441
#define KPAD 448
#define CSTR 456   // cor row stride in shorts

typedef __attribute__((ext_vector_type(8))) short bf16x8;
typedef __attribute__((ext_vector_type(4))) float f32x4;

#define MFMA16(a,b,c) __builtin_amdgcn_mfma_f32_16x16x32_bf16(a,b,c,0,0,0)

__device__ __forceinline__ short f2bf(float f){
  unsigned u = __float_as_uint(f);
  return (short)((u + 0x7FFFu + ((u >> 16) & 1u)) >> 16);
}

// Fragment load from transposed bf16 tensor X[plane][row][w][c] (c innermost).
// Matrix element [i = tile*16 + (lane&15)][k-ch = kk*32 + (lane>>4)*8 + j] at
// w = 2*i + pi  ->  one contiguous 16-byte load per lane.
__device__ __forceinline__ bf16x8 load_fragX(const short* rowX, int pi, int tile,
                                             int kk, int lane){
  const int m = lane & 15, kg = lane >> 4;
  return *(const bf16x8*)(rowX + (2*(tile*16 + m) + pi)*64 + kk*32 + kg*8);
}

// ---------------- Pass 0: fp32 [pl][c][h][w] -> bf16 X[pl-plane0][h][w][c] ----------------
__global__ __launch_bounds__(256,4) void k_transpose(const float* __restrict__ feats,
                                                     short* __restrict__ X, int plane0)
{
  __shared__ float tile[64*65];
  const int tid = threadIdx.x;
  const int pll = blockIdx.x >> 6, h = blockIdx.x & 63;
  const float* pb = feats + (size_t)(plane0 + pll)*CHW + h*64;
#pragma unroll
  for (int k = 0; k < 4; ++k){
    const int idx = tid + k*256;
    const int c = idx >> 4, w4 = idx & 15;
    f32x4 v = *(const f32x4*)(pb + c*HW + w4*4);
#pragma unroll
    for (int j = 0; j < 4; ++j) tile[c*65 + w4*4 + j] = v[j];
  }
  __syncthreads();
  short* xb = X + ((size_t)pll*64 + h)*4096;
#pragma unroll
  for (int s = 0; s < 2; ++s){
    const int chunk = tid + s*256;
    const int w = chunk >> 3, cg = chunk & 7;
    bf16x8 r;
#pragma unroll
    for (int j = 0; j < 8; ++j) r[j] = f2bf(tile[(cg*8 + j)*65 + w]);
    *(bf16x8*)(xb + w*64 + cg*8) = r;
  }
}

// ---------------- Pass 1: correlation Gram + BN statistics ----------------
__global__ __launch_bounds__(256,2) void k_stats(const short* __restrict__ X,
                                                 float* __restrict__ gsum,
                                                 float* __restrict__ gssq,
                                                 int n0, int plane0)
{
  __shared__ float Gbuf[4*1056];
  __shared__ float s_sum[2][NPQ];
  __shared__ float s_ssq[2][NPQ];
  const int tid = threadIdx.x, wv = tid >> 6, lane = tid & 63;
  const int nn = n0 + (blockIdx.x >> 6), h = blockIdx.x & 63;
  const int pl1 = (nn/7)*8 + (nn%7) - plane0;
  const short* f1r  = X + ((size_t)pl1*64 + h)*4096;
  const short* f2pl = X + (size_t)(pl1 + 1)*64*4096;
  float* Gw = Gbuf + wv*1056;

  for (int i = tid; i < 2*NPQ; i += 256){
    (&s_sum[0][0])[i] = 0.f; (&s_ssq[0][0])[i] = 0.f;
  }
  __syncthreads();

  bf16x8 afr[2][2];
  int cur_pi = -1;
  for (int it = 0; it < 11; ++it){
    const int u = it*4 + wv;
    const bool active = (u < 42);
    const int pi = (u >= 21) ? 1 : 0;
    const int p  = u - pi*21;
    const int row = h + 2*p - 20;
    const bool rv = active && ((unsigned)row < 64u);

    if (active && pi != cur_pi){
#pragma unroll
      for (int mt = 0; mt < 2; ++mt)
#pragma unroll
        for (int kk = 0; kk < 2; ++kk)
          afr[mt][kk] = load_fragX(f1r, pi, mt, kk, lane);
      cur_pi = pi;
    }

    if (rv){
      const short* f2r = f2pl + row*4096;
      f32x4 a00 = {0.f,0.f,0.f,0.f}, a01 = a00, a10 = a00, a11 = a00;
#pragma unroll
      for (int kk = 0; kk < 2; ++kk){
        bf16x8 b0 = load_fragX(f2r, pi, 0, kk, lane);
        bf16x8 b1 = load_fragX(f2r, pi, 1, kk, lane);
        a00 = MFMA16(afr[0][kk], b0, a00);
        a01 = MFMA16(afr[0][kk], b1, a01);
        a10 = MFMA16(afr[1][kk], b0, a10);
        a11 = MFMA16(afr[1][kk], b1, a11);
      }
      const int cI = (lane >> 4)*4;       // C-layout: row=(lane>>4)*4+reg, col=lane&15
      const int cJ = lane & 15;
#pragma unroll
      for (int r = 0; r < 4; ++r){
        Gw[(cJ     )*33 + cI + r     ] = a00[r];
        Gw[(cJ + 16)*33 + cI + r     ] = a01[r];
        Gw[(cJ     )*33 + cI + r + 16] = a10[r];
        Gw[(cJ + 16)*33 + cI + r + 16] = a11[r];
      }
    }
    __syncthreads();

    if (rv){
      const int q = lane / 3;
      const int seg = lane - q*3;
      float s = 0.f, s2 = 0.f;
      if (lane < 63){
        const int i0 = seg*11;
        const int i1 = (seg == 2) ? 32 : i0 + 11;
        for (int i = i0; i < i1; ++i){
          const int j = i + q - 10;
          if ((unsigned)j < 32u){
            float v = Gw[j*33 + i];
            s += v; s2 += v*v;
          }
        }
      }
      float sA = __shfl(s,  lane+1), sB = __shfl(s,  lane+2);
      float tA = __shfl(s2, lane+1), tB = __shfl(s2, lane+2);
      if (lane < 63 && seg == 0){
        s_sum[pi][p*21 + q] += s + sA + sB;   // (pi,p) unique per wave: no race
        s_ssq[pi][p*21 + q] += s2 + tA + tB;
      }
    }
  }
  __syncthreads();

  for (int i = tid; i < NPQ; i += 256){
    atomicAdd(&gsum[i], s_sum[0][i] + s_sum[1][i]);
    atomicAdd(&gssq[i], s_ssq[0][i] + s_ssq[1][i]);
  }
}

// ---------------- Pass 2a: fold BN into conv weights ----------------
__global__ __launch_bounds__(256) void k_finalize(const float* __restrict__ gsum,
    const float* __restrict__ gssq, const float* __restrict__ gamma,
    const float* __restrict__ beta, const float* __restrict__ convw,
    short* __restrict__ wpT, float* __restrict__ bias)
{
  __shared__ float s_scale[NPQ], s_shift[NPQ];
  const int tid = threadIdx.x;
  for (int k = tid; k < NPQ; k += 256){
    float m  = gsum[k] * (1.f/114688.f);
    float v  = gssq[k] * (1.f/114688.f) - m*m;
    float iv = rsqrtf(v + 1e-5f);
    float sc = gamma[k] * iv;
    s_scale[k] = sc;
    s_shift[k] = beta[k] - m*sc;
  }
  __syncthreads();
  for (int idx = tid; idx < 64*KPAD; idx += 256){
    int o = idx / KPAD, k = idx - o*KPAD;
    float w = (k < NPQ) ? convw[o*NPQ + k] * s_scale[k] : 0.f;
    wpT[idx] = f2bf(w);
  }
  if (tid < 64){
    float b = 0.f;
    for (int k = 0; k < NPQ; ++k) b += s_shift[k] * convw[tid*NPQ + k];
    bias[tid] = b;
  }
}

// ---------------- Pass 2b: recompute Gram, register-scatter band, fused conv ----------------
__global__ __launch_bounds__(256,2) void k_main(const short* __restrict__ X,
    const short* __restrict__ wpT, const float* __restrict__ bias,
    float* __restrict__ out, int n0, int plane0)
{
  __shared__ __align__(16) short cor[64*CSTR];
  const int tid = threadIdx.x, wv = tid >> 6, lane = tid & 63;
  const int nn = n0 + (blockIdx.x >> 6), h = blockIdx.x & 63;
  const int pl1g = (nn/7)*8 + (nn%7);
  const int pl1 = pl1g - plane0;
  const short* f1r  = X + ((size_t)pl1*64 + h)*4096;
  const short* f2pl = X + (size_t)(pl1 + 1)*64*4096;

  {
    int4 z = {0,0,0,0};
    for (int idx = tid; idx < 64*CSTR/8; idx += 256) ((int4*)cor)[idx] = z;
  }
  __syncthreads();

  bf16x8 afr[2][2];
  int cur_pi = -1;
  for (int it = 0; it < 11; ++it){        // no per-iter barriers: cor regions disjoint
    const int u = it*4 + wv;
    const bool active = (u < 42);
    const int pi = (u >= 21) ? 1 : 0;
    const int p  = u - pi*21;
    const int row = h + 2*p - 20;
    const bool rv = active && ((unsigned)row < 64u);

    if (active && pi != cur_pi){
#pragma unroll
      for (int mt = 0; mt < 2; ++mt)
#pragma unroll
        for (int kk = 0; kk < 2; ++kk)
          afr[mt][kk] = load_fragX(f1r, pi, mt, kk, lane);
      cur_pi = pi;
    }

    if (rv){
      const short* f2r = f2pl + row*4096;
      f32x4 a00 = {0.f,0.f,0.f,0.f}, a01 = a00, a10 = a00, a11 = a00;
#pragma unroll
      for (int kk = 0; kk < 2; ++kk){
        bf16x8 b0 = load_fragX(f2r, pi, 0, kk, lane);
        bf16x8 b1 = load_fragX(f2r, pi, 1, kk, lane);
        a00 = MFMA16(afr[0][kk], b0, a00);
        a01 = MFMA16(afr[0][kk], b1, a01);
        a10 = MFMA16(afr[1][kk], b0, a10);
        a11 = MFMA16(afr[1][kk], b1, a11);
      }
      const int cI = (lane >> 4)*4;
      const int cJ = lane & 15;
      const int p21 = p*21;
      // direct register -> band scatter: G[i][j] -> cor[2i+pi][p*21 + (j-i+10)]
#define SCAT(v, ii, jj) do{ int q_ = (jj) - (ii) + 10; \
        if ((unsigned)q_ < 21u) cor[(2*(ii)+pi)*CSTR + p21 + q_] = f2bf(v); }while(0)
#pragma unroll
      for (int r = 0; r < 4; ++r){
        const int i0 = cI + r;
        SCAT(a00[r], i0,      cJ);
        SCAT(a01[r], i0,      cJ + 16);
        SCAT(a10[r], i0 + 16, cJ);
        SCAT(a11[r], i0 + 16, cJ + 16);
      }
#undef SCAT
    }
  }
  __syncthreads();

  // GEMM2: D[o][pix] = sum_k wpT[o][k] * cor[pix][k]
  const int m = lane & 15, kg = lane >> 4;
  const short* wrow = wpT + (wv*16 + m)*KPAD;
  f32x4 acc[4];
#pragma unroll
  for (int nt = 0; nt < 4; ++nt) acc[nt] = (f32x4){0.f,0.f,0.f,0.f};
  for (int kk = 0; kk < 14; ++kk){
    const int k0 = kk*32 + kg*8;
    bf16x8 aw = *(const bf16x8*)(wrow + k0);
#pragma unroll
    for (int nt = 0; nt < 4; ++nt){
      bf16x8 bc = *(const bf16x8*)&cor[(nt*16 + m)*CSTR + k0];
      acc[nt] = MFMA16(aw, bc, acc[nt]);
    }
  }
  const int r0 = (lane >> 4)*4;
  float bo[4];
#pragma unroll
  for (int r = 0; r < 4; ++r) bo[r] = bias[wv*16 + r0 + r];
  float* outb = out + (size_t)pl1g*CHW + h*64;
#pragma unroll
  for (int nt = 0; nt < 4; ++nt)
#pragma unroll
    for (int r = 0; r < 4; ++r){
      const int o = wv*16 + r0 + r;
      outb[o*HW + nt*16 + m] = acc[nt][r] + bo[r];
    }
}

// ---------------- zero frame T=7 ----------------
__global__ __launch_bounds__(256) void k_zero(float* __restrict__ out){
  const int idx = blockIdx.x*256 + threadIdx.x;
  const int b = idx >> 16, r = idx & 65535;
  float4* p = (float4*)(out + (size_t)(b*8 + 7)*CHW);
  p[r] = make_float4(0.f, 0.f, 0.f, 0.f);
}

extern "C" void kernel_launch(void* const* d_in, const int* in_sizes, int n_in,
                              void* d_out, int out_size, void* d_ws, size_t ws_size,
                              hipStream_t stream)
{
  const float* feats = (const float*)d_in[0];
  const float* gamma = (const float*)d_in[1];
  const float* beta  = (const float*)d_in[2];
  const float* convw = (const float*)d_in[3];
  float* out = (float*)d_out;
  float* wsf = (float*)d_ws;
  float* gsum = wsf;                    // floats [0, 441)
  float* gssq = wsf + 441;              // floats [441, 882)
  float* bias = wsf + 896;              // floats [896, 960)
  short* wpT  = (short*)(wsf + 1024);   // 64*448 shorts = 14336 floats: [1024, 15360)
  short* X    = (short*)(wsf + 16384);  // starts PAST wpT (R2/R3 bug: was 8192, inside wpT)

  const size_t fixedB = 16384*sizeof(float);
  const size_t planeB = (size_t)CHW*2;             // 512 KB per bf16 plane

  hipMemsetAsync(gsum, 0, 882*sizeof(float), stream);
  k_zero<<<1024, 256, 0, stream>>>(out);

  if (ws_size >= fixedB + 32*planeB){
    // Tier A: all 32 planes resident, transpose once
    k_transpose<<<2048, 256, 0, stream>>>(feats, X, 0);
    k_stats<<<1792, 256, 0, stream>>>(X, gsum, gssq, 0, 0);
    k_finalize<<<1, 256, 0, stream>>>(gsum, gssq, gamma, beta, convw, wpT, bias);
    k_main<<<1792, 256, 0, stream>>>(X, wpT, bias, out, 0, 0);
  } else if (ws_size >= fixedB + 8*planeB){
    // Tier B: per-batch chunks (8 planes); transpose twice
    for (int b = 0; b < 4; ++b){
      k_transpose<<<512, 256, 0, stream>>>(feats, X, b*8);
      k_stats<<<448, 256, 0, stream>>>(X, gsum, gssq, b*7, b*8);
    }
    k_finalize<<<1, 256, 0, stream>>>(gsum, gssq, gamma, beta, convw, wpT, bias);
    for (int b = 0; b < 4; ++b){
      k_transpose<<<512, 256, 0, stream>>>(feats, X, b*8);
      k_main<<<448, 256, 0, stream>>>(X, wpT, bias, out, b*7, b*8);
    }
  } else {
    // Tier C: per-pair chunks (2 planes) — safety net
    for (int n = 0; n < 28; ++n){
      const int pl = (n/7)*8 + (n%7);
      k_transpose<<<128, 256, 0, stream>>>(feats, X, pl);
      k_stats<<<64, 256, 0, stream>>>(X, gsum, gssq, n, pl);
    }
    k_finalize<<<1, 256, 0, stream>>>(gsum, gssq, gamma, beta, convw, wpT, bias);
    for (int n = 0; n < 28; ++n){
      const int pl = (n/7)*8 + (n%7);
      k_transpose<<<128, 256, 0, stream>>>(feats, X, pl);
      k_main<<<64, 256, 0, stream>>>(X, wpT, bias, out, n, pl);
    }
  }
}